// Round 1
// 632.960 us; speedup vs baseline: 1.0338x; 1.0338x over previous
//
#include <hip/hip_runtime.h>
#include <hip/hip_bf16.h>

#define EPS 1e-5f

// Per the HW-verified guide: bf16 MFMA fragments are 8 x short (4 VGPRs).
typedef short bf16x8 __attribute__((ext_vector_type(8)));
typedef float f32x4  __attribute__((ext_vector_type(4)));

union BF8 { ushort u[8]; bf16x8 v; };

__device__ __forceinline__ ushort f2bf(float f) {
  uint u = __float_as_uint(f);
  u += 0x7fffu + ((u >> 16) & 1u);   // RNE
  return (ushort)(u >> 16);
}
__device__ __forceinline__ float bf2f(ushort u) {
  return __uint_as_float(((uint)u) << 16);
}
__device__ __forceinline__ f32x4 mfma16(bf16x8 a, bf16x8 b, f32x4 c) {
  return __builtin_amdgcn_mfma_f32_16x16x32_bf16(a, b, c, 0, 0, 0);
}

// ---------------------------------------------------------------------------
// zero: clears the atomic accumulators (rp+G+S, 0x604000 bytes) in scratch.
// ---------------------------------------------------------------------------
__global__ __launch_bounds__(256) void k_zero(float4* __restrict__ p) {
  p[blockIdx.x * 256 + threadIdx.x] = make_float4(0.f, 0.f, 0.f, 0.f);
}

// ---------------------------------------------------------------------------
// prep: cast wdr/wdrs to bf16 (fold 1/49 into wdrs), fold BN1 consts,
// transpose wfc -> wfcT[p][c]
// ---------------------------------------------------------------------------
__global__ __launch_bounds__(256) void k_prep(
    const float* __restrict__ wdr, const float* __restrict__ wdrs,
    const float* __restrict__ bdr,
    const float* __restrict__ g1, const float* __restrict__ be1,
    const float* __restrict__ m1, const float* __restrict__ v1,
    const float* __restrict__ wfc,
    ushort* __restrict__ wdr_bf, ushort* __restrict__ wdrs_bf,
    float* __restrict__ sc1, float* __restrict__ sh1,
    float* __restrict__ wfcT) {
  int i = blockIdx.x * 256 + threadIdx.x;   // grid 1024 -> 262144
  if (i < 65536) {
    wdr_bf[i]  = f2bf(wdr[i]);
    wdrs_bf[i] = f2bf(wdrs[i] * (1.0f / 49.0f));
  }
  if (i < 262144) {
    int c = i >> 9, p = i & 511;
    wfcT[p * 512 + c] = wfc[i];
  }
  if (i < 128) {
    float a = g1[i] / sqrtf(v1[i] + EPS);
    sc1[i] = a;
    sh1[i] = (bdr[i] - m1[i]) * a + be1[i];
  }
}

// ---------------------------------------------------------------------------
// conv y: per (batch, 128-position tile). GEMM M=128,K=512 with relu(x)
// staged to LDS (k-contiguous swizzled layout), BN1+relu epilogue -> y_bf.
// Also accumulates pooled relu(x) sums into rp[b][g][c] (g-major!).
//
// v2: software-pipelined. Register double-buffer (rA/rB) prefetches chunk
// kc+1's 32 KB of x while chunk kc is processed; LDS + pool double-buffered
// so the loop needs ONE barrier per chunk instead of two. The load latency
// (previously fully exposed per chunk: all utils <10%, 5x off the 37 us
// memory roofline) now hides under the process-VALU + MFMA + flush phases.
// ---------------------------------------------------------------------------
__global__ __launch_bounds__(256) void k_convy(
    const float* __restrict__ x, const ushort* __restrict__ wdr_bf,
    const float* __restrict__ sc1, const float* __restrict__ sh1,
    ushort* __restrict__ y_bf, float* __restrict__ rp) {
  __shared__ ushort xs[2][9216];     // 2 x 18432 B: (k>>3)*1152 + (n>>3)*72 + (n&7)*8 + (k&7)
  __shared__ float pool[2][1024];    // 2 x [c_in_chunk 64][local bin 16]
  __shared__ float sc_s[128], sh_s[128];

  const int t  = threadIdx.x;
  const int b  = blockIdx.y;
  const int n0 = blockIdx.x * 128;

  if (t < 128) { sc_s[t] = sc1[t]; sh_s[t] = sh1[t]; }
#pragma unroll
  for (int f = 0; f < 4; f++) { pool[0][t + f * 256] = 0.f; pool[1][t + f * 256] = 0.f; }

  // staging coords: thread loads float4 (4 positions) of one channel
  const int cl = t & 7;         // channel-in-8
  const int nq = t >> 3;        // 0..31 -> position quad
  const int nl = nq * 4;
  const int ng = n0 + nl;
  const bool nv = ng < 3136;
  const int h   = ng / 56;
  const int w   = ng - h * 56;           // 56%4==0 -> quad never crosses a row
  const int gh0 = (n0 / 56) / 7;
  const int lb0 = (h / 7 - gh0) * 8 + (w / 7);
  const int lb3 = (h / 7 - gh0) * 8 + ((w + 3) / 7);
  int split = 7 - (w % 7); if (split > 4) split = 4;  // elems [0,split) in lb0
  const int ng8  = nq >> 1;
  const int nsub = (nq & 1) * 4;

  // wave coords (2x2 over 128x128 tile, each wave 64x64 = 4x4 mfma frags)
  const int l  = t & 63;
  const int wv = t >> 6;
  const int wr = wv >> 1, wc = wv & 1;
  const int lm = l & 15,  lk = l >> 4;

  const float* xb = x + (size_t)(b * 512) * 3136 + ng;   // + c*3136 per channel

  f32x4 acc[4][4];
#pragma unroll
  for (int a = 0; a < 4; a++)
#pragma unroll
    for (int c = 0; c < 4; c++) acc[a][c] = (f32x4){0.f, 0.f, 0.f, 0.f};

  const float4 z4 = make_float4(0.f, 0.f, 0.f, 0.f);
  float4 rA[8], rB[8];

  // prologue: chunk 0 loads in flight
#pragma unroll
  for (int r = 0; r < 8; r++) {
    rA[r] = z4;
    if (nv) rA[r] = *(const float4*)(xb + (size_t)(r * 8 + cl) * 3136);
  }

  __syncthreads();  // pool zero + sc_s visible (also drains prologue loads)

  for (int kc = 0; kc < 8; kc++) {
    // ---- issue NEXT chunk's global loads (overlap with everything below) ----
    if (kc < 7) {
#pragma unroll
      for (int r = 0; r < 8; r++) {
        rB[r] = z4;
        if (nv) rB[r] = *(const float4*)(xb + (size_t)((kc + 1) * 64 + r * 8 + cl) * 3136);
      }
    }

    // ---- process current regs: relu + pool + bf16 -> LDS buf[kc&1] ----
    ushort* xsb = xs[kc & 1];
    float*  plb = pool[kc & 1];
#pragma unroll
    for (int r = 0; r < 8; r++) {
      int cc = r * 8 + cl;          // 0..63
      float e0 = fmaxf(rA[r].x, 0.f), e1 = fmaxf(rA[r].y, 0.f);
      float e2 = fmaxf(rA[r].z, 0.f), e3 = fmaxf(rA[r].w, 0.f);
      if (nv) {
        float s0 = e0, s1 = 0.f;
        if (split > 1) s0 += e1; else s1 += e1;
        if (split > 2) s0 += e2; else s1 += e2;
        if (split > 3) s0 += e3; else s1 += e3;
        atomicAdd(&plb[cc * 16 + lb0], s0);
        if (lb3 != lb0) atomicAdd(&plb[cc * 16 + lb3], s1);
      }
      int base = (cc >> 3) * 1152 + ng8 * 72 + nsub * 8 + (cc & 7);
      xsb[base]      = f2bf(e0);
      xsb[base + 8]  = f2bf(e1);
      xsb[base + 16] = f2bf(e2);
      xsb[base + 24] = f2bf(e3);
    }
    __syncthreads();   // single barrier per chunk (dbuf makes 2nd unnecessary)

    // ---- MFMA over this 64-deep K chunk ----
#pragma unroll
    for (int ki = 0; ki < 2; ki++) {
      bf16x8 af[4], bfr[4];
#pragma unroll
      for (int mi = 0; mi < 4; mi++) {
        int m = wr * 64 + mi * 16 + lm;
        af[mi] = *(const bf16x8*)(wdr_bf + m * 512 + kc * 64 + ki * 32 + lk * 8);
      }
#pragma unroll
      for (int ni = 0; ni < 4; ni++) {
        int n = wc * 64 + ni * 16 + lm;
        int a = (ki * 4 + lk) * 1152 + (n >> 3) * 72 + (n & 7) * 8;
        bfr[ni] = *(const bf16x8*)(xsb + a);
      }
#pragma unroll
      for (int mi = 0; mi < 4; mi++)
#pragma unroll
        for (int ni = 0; ni < 4; ni++)
          acc[mi][ni] = mfma16(af[mi], bfr[ni], acc[mi][ni]);
    }

    // ---- flush pooled sums for this channel chunk, re-zero ----
    // safe: pool[kc&1] atomics all landed before barrier(kc); next use of
    // this buffer (chunk kc+2's atomics) is after barrier(kc+1), by which
    // point this wave's zero-write has drained (lgkmcnt at its barrier).
#pragma unroll
    for (int f = 0; f < 4; f++) {
      int idx = t + f * 256;
      float pv = plb[idx];
      int cL = idx >> 4, lb = idx & 15;
      int gbin = gh0 * 8 + lb;
      if (pv != 0.f && gbin < 64)
        atomicAdd(&rp[((size_t)(b * 64 + gbin)) * 512 + kc * 64 + cL], pv);
      plb[idx] = 0.f;
    }

    // ---- rotate prefetch regs (static indices, no scratch) ----
    if (kc < 7) {
#pragma unroll
      for (int r = 0; r < 8; r++) rA[r] = rB[r];
    }
  }

  // ---- epilogue: BN1 + relu, store bf16 y ----
#pragma unroll
  for (int mi = 0; mi < 4; mi++) {
#pragma unroll
    for (int ni = 0; ni < 4; ni++) {
      int n_g = n0 + wc * 64 + ni * 16 + lm;
      if (n_g >= 3136) continue;
#pragma unroll
      for (int r = 0; r < 4; r++) {
        int m = wr * 64 + mi * 16 + lk * 4 + r;
        float v = acc[mi][ni][r] * sc_s[m] + sh_s[m];
        v = fmaxf(v, 0.f);
        y_bf[((size_t)(b * 128 + m)) * 3136 + n_g] = f2bf(v);
      }
    }
  }
}

// ---------------------------------------------------------------------------
// Gram: G[b] += Y Y^T over a 448-wide K slice; also row sums S.
// grid (7, 32). Both MFMA operands come from the same LDS slab.
// v2: register prefetch + LDS double-buffer -> one barrier per K-step.
// ---------------------------------------------------------------------------
__global__ __launch_bounds__(256) void k_gram(
    const ushort* __restrict__ y_bf, float* __restrict__ G, float* __restrict__ S) {
  __shared__ ushort ys[2][128 * 40];   // stride 80B (pad) per row, x2 buffers
  const int t  = threadIdx.x;
  const int b  = blockIdx.y;
  const int k0 = blockIdx.x * 448;

  const int l  = t & 63, wv = t >> 6;
  const int wr = wv >> 1, wc = wv & 1;
  const int lm = l & 15,  lk = l >> 4;

  const int mA = t >> 2, k8 = t & 3;
  const ushort* yb = y_bf + ((size_t)(b * 128 + mA)) * 3136 + k0 + k8 * 8;
  const size_t rowoff = (size_t)64 * 3136;

  f32x4 acc[4][4];
#pragma unroll
  for (int a = 0; a < 4; a++)
#pragma unroll
    for (int c = 0; c < 4; c++) acc[a][c] = (f32x4){0.f, 0.f, 0.f, 0.f};
  float sA = 0.f, sB = 0.f;

  BF8 a0, a1, b0, b1;
  a0.v = *(const bf16x8*)(yb);
  a1.v = *(const bf16x8*)(yb + rowoff);

  for (int kc = 0; kc < 14; kc++) {
    // prefetch next K-step while current is processed + MFMA'd
    if (kc < 13) {
      b0.v = *(const bf16x8*)(yb + (kc + 1) * 32);
      b1.v = *(const bf16x8*)(yb + rowoff + (kc + 1) * 32);
    }
#pragma unroll
    for (int j = 0; j < 8; j++) { sA += bf2f(a0.u[j]); sB += bf2f(a1.u[j]); }
    ushort* ysb = ys[kc & 1];
    *(bf16x8*)(ysb + mA * 40 + k8 * 8) = a0.v;
    *(bf16x8*)(ysb + (mA + 64) * 40 + k8 * 8) = a1.v;
    __syncthreads();

    bf16x8 af[4], bfr[4];
#pragma unroll
    for (int mi = 0; mi < 4; mi++)
      af[mi] = *(const bf16x8*)(ysb + (wr * 64 + mi * 16 + lm) * 40 + lk * 8);
#pragma unroll
    for (int ni = 0; ni < 4; ni++)
      bfr[ni] = *(const bf16x8*)(ysb + (wc * 64 + ni * 16 + lm) * 40 + lk * 8);
#pragma unroll
    for (int mi = 0; mi < 4; mi++)
#pragma unroll
      for (int ni = 0; ni < 4; ni++)
        acc[mi][ni] = mfma16(af[mi], bfr[ni], acc[mi][ni]);

    if (kc < 13) { a0 = b0; a1 = b1; }
  }

#pragma unroll
  for (int mi = 0; mi < 4; mi++)
#pragma unroll
    for (int ni = 0; ni < 4; ni++)
#pragma unroll
      for (int r = 0; r < 4; r++) {
        int i = wr * 64 + mi * 16 + lk * 4 + r;
        int j = wc * 64 + ni * 16 + lm;
        atomicAdd(&G[((size_t)(b * 128 + i)) * 128 + j], acc[mi][ni][r]);
      }
  atomicAdd(&S[b * 128 + mA], sA);
  atomicAdd(&S[b * 128 + mA + 64], sB);
}

// ---------------------------------------------------------------------------
// catt: cov -> BN2 -> vch -> sigmoid(vch @ wfc^T + bfc). grid 32.
// ---------------------------------------------------------------------------
__global__ __launch_bounds__(256) void k_catt(
    const float* __restrict__ G, const float* __restrict__ S,
    const float* __restrict__ g2, const float* __restrict__ be2,
    const float* __restrict__ m2, const float* __restrict__ v2,
    const float* __restrict__ wrow, const float* __restrict__ brow,
    const float* __restrict__ wfcT, const float* __restrict__ bfc,
    float* __restrict__ catt) {
  __shared__ float Ss[128];
  __shared__ float vch_s[512];
  const int t = threadIdx.x;
  const int b = blockIdx.x;
  const float invM = 1.0f / 3136.0f;
  if (t < 128) Ss[t] = S[b * 128 + t];
  __syncthreads();
#pragma unroll
  for (int rep = 0; rep < 2; rep++) {
    int p = t + rep * 256;
    int i = p >> 2, j = p & 3;
    float a2  = g2[i] / sqrtf(v2[i] + EPS);
    float mi2 = m2[i], bei = be2[i];
    float Si  = Ss[i] * invM;
    const float* Grow = G + ((size_t)(b * 128 + i)) * 128;
    const float* wr_  = wrow + (i * 4 + j) * 128;
    float a = 0.f;
    for (int k = 0; k < 128; k++) {
      float cov = (Grow[k] - Si * Ss[k]) * invM;
      a += ((cov - mi2) * a2 + bei) * wr_[k];
    }
    vch_s[p] = a + brow[p];
  }
  __syncthreads();
#pragma unroll
  for (int rep = 0; rep < 2; rep++) {
    int c = t + rep * 256;
    float z = bfc[c];
    for (int p = 0; p < 512; p++) z += vch_s[p] * wfcT[p * 512 + c];
    catt[b * 512 + c] = 1.f / (1.f + expf(-z));
  }
}

// ---------------------------------------------------------------------------
// sconv: sf = BN3(wdrs_bf @ (rp) + bdrs); rp stored [b][g][c] so K contiguous.
// Output sfT[b][g][d] bf16. grid 32.
// ---------------------------------------------------------------------------
__global__ __launch_bounds__(256) void k_sconv(
    const float* __restrict__ rp, const ushort* __restrict__ wdrs_bf,
    const float* __restrict__ bdrs,
    const float* __restrict__ g3, const float* __restrict__ be3,
    const float* __restrict__ m3, const float* __restrict__ v3,
    ushort* __restrict__ sfT) {
  const int t = threadIdx.x;
  const int b = blockIdx.x;
  const int l = t & 63, wv = t >> 6;
  const int wm = wv >> 1, wn = wv & 1;
  const int lm = l & 15,  lk = l >> 4;
  f32x4 acc[4][2];
#pragma unroll
  for (int a = 0; a < 4; a++) { acc[a][0] = (f32x4){0.f,0.f,0.f,0.f}; acc[a][1] = (f32x4){0.f,0.f,0.f,0.f}; }

  for (int kk = 0; kk < 16; kk++) {
    bf16x8 af[4], bfr[2];
#pragma unroll
    for (int mi = 0; mi < 4; mi++) {
      int m = wm * 64 + mi * 16 + lm;
      af[mi] = *(const bf16x8*)(wdrs_bf + m * 512 + kk * 32 + lk * 8);
    }
#pragma unroll
    for (int ni = 0; ni < 2; ni++) {
      int g = wn * 32 + ni * 16 + lm;
      const float* pb = rp + ((size_t)(b * 64 + g)) * 512 + kk * 32 + lk * 8;
      float4 fa = *(const float4*)pb;
      float4 fb = *(const float4*)(pb + 4);
      BF8 bb;
      bb.u[0] = f2bf(fa.x); bb.u[1] = f2bf(fa.y); bb.u[2] = f2bf(fa.z); bb.u[3] = f2bf(fa.w);
      bb.u[4] = f2bf(fb.x); bb.u[5] = f2bf(fb.y); bb.u[6] = f2bf(fb.z); bb.u[7] = f2bf(fb.w);
      bfr[ni] = bb.v;
    }
#pragma unroll
    for (int mi = 0; mi < 4; mi++)
#pragma unroll
      for (int ni = 0; ni < 2; ni++)
        acc[mi][ni] = mfma16(af[mi], bfr[ni], acc[mi][ni]);
  }
#pragma unroll
  for (int mi = 0; mi < 4; mi++)
#pragma unroll
    for (int ni = 0; ni < 2; ni++) {
      int g = wn * 32 + ni * 16 + lm;
#pragma unroll
      for (int r = 0; r < 4; r++) {
        int d = wm * 64 + mi * 16 + lk * 4 + r;
        float a3 = g3[d] / sqrtf(v3[d] + EPS);
        float sf = (acc[mi][ni][r] + bdrs[d] - m3[d]) * a3 + be3[d];
        sfT[((size_t)(b * 64 + g)) * 128 + d] = f2bf(sf);
      }
    }
}

// ---------------------------------------------------------------------------
// patt: covs (64x64 MFMA) -> BN4 -> vs(relu) -> sigmoid(vs @ wfcs^T). grid 32.
// ---------------------------------------------------------------------------
__global__ __launch_bounds__(256) void k_patt(
    const ushort* __restrict__ sfT,
    const float* __restrict__ g4, const float* __restrict__ be4,
    const float* __restrict__ m4, const float* __restrict__ v4,
    const float* __restrict__ wrows, const float* __restrict__ brows,
    const float* __restrict__ wfcs, const float* __restrict__ bfcs,
    float* __restrict__ patt) {
  __shared__ float colsum_s[64];
  __shared__ float covbn_s[64 * 65];
  __shared__ float vs_s[256];
  const int t = threadIdx.x;
  const int b = blockIdx.x;
  if (t < 64) {
    float cs = 0.f;
    const ushort* row = sfT + ((size_t)(b * 64 + t)) * 128;
    for (int dq = 0; dq < 16; dq++) {
      BF8 v; v.v = *(const bf16x8*)(row + dq * 8);
#pragma unroll
      for (int j = 0; j < 8; j++) cs += bf2f(v.u[j]);
    }
    colsum_s[t] = cs;
  }
  __syncthreads();

  const int l = t & 63, wv = t >> 6;
  const int wr = wv >> 1, wc = wv & 1;
  const int lm = l & 15,  lk = l >> 4;
  f32x4 acc[2][2];
  acc[0][0] = (f32x4){0.f,0.f,0.f,0.f}; acc[0][1] = (f32x4){0.f,0.f,0.f,0.f};
  acc[1][0] = (f32x4){0.f,0.f,0.f,0.f}; acc[1][1] = (f32x4){0.f,0.f,0.f,0.f};
  for (int kk = 0; kk < 4; kk++) {
    bf16x8 af[2], bfr[2];
#pragma unroll
    for (int mi = 0; mi < 2; mi++)
      af[mi] = *(const bf16x8*)(sfT + ((size_t)(b * 64 + wr * 32 + mi * 16 + lm)) * 128 + kk * 32 + lk * 8);
#pragma unroll
    for (int ni = 0; ni < 2; ni++)
      bfr[ni] = *(const bf16x8*)(sfT + ((size_t)(b * 64 + wc * 32 + ni * 16 + lm)) * 128 + kk * 32 + lk * 8);
#pragma unroll
    for (int mi = 0; mi < 2; mi++)
#pragma unroll
      for (int ni = 0; ni < 2; ni++)
        acc[mi][ni] = mfma16(af[mi], bfr[ni], acc[mi][ni]);
  }
  const float inv64 = 1.0f / 64.0f;
#pragma unroll
  for (int mi = 0; mi < 2; mi++)
#pragma unroll
    for (int ni = 0; ni < 2; ni++) {
      int j = wc * 32 + ni * 16 + lm;
#pragma unroll
      for (int r = 0; r < 4; r++) {
        int i = wr * 32 + mi * 16 + lk * 4 + r;
        float cv = (acc[mi][ni][r] - colsum_s[i] * colsum_s[j] * inv64) * inv64;
        float a4 = g4[i] / sqrtf(v4[i] + EPS);
        covbn_s[i * 65 + j] = (cv - m4[i]) * a4 + be4[i];
      }
    }
  __syncthreads();
  {
    int m = t >> 2, j = t & 3;
    float a = brows[t];
    const float* wr_ = wrows + (m * 4 + j) * 64;
    for (int k = 0; k < 64; k++) a += covbn_s[m * 65 + k] * wr_[k];
    vs_s[t] = fmaxf(a, 0.f);
  }
  __syncthreads();
  if (t < 64) {
    float z = bfcs[t];
    const float* wf = wfcs + t * 256;
    for (int p = 0; p < 256; p++) z += vs_s[p] * wf[p];
    patt[b * 64 + t] = 1.f / (1.f + expf(-z));
  }
}

// ---------------------------------------------------------------------------
// final: out = x*catt + relu(x*patt). grid 50176 x 256, one float4/thread.
// ---------------------------------------------------------------------------
__global__ __launch_bounds__(256) void k_final(
    const float* __restrict__ x, const float* __restrict__ catt,
    const float* __restrict__ patt, float* __restrict__ out) {
  int gi = blockIdx.x * 256 + threadIdx.x;   // quad index
  int bc = gi / 784;                         // b*512 + c
  int q  = gi - bc * 784;
  int n  = q * 4;
  int b  = bc >> 9;
  float ca = catt[bc];
  int h = n / 56;
  int w = n - h * 56;
  const float* pp = patt + b * 64 + (h / 7) * 8;
  float p0 = pp[w / 7], p1 = pp[(w + 1) / 7], p2 = pp[(w + 2) / 7], p3 = pp[(w + 3) / 7];
  float4 xv = *(const float4*)(x + (size_t)gi * 4);
  float4 o;
  o.x = xv.x * ca + fmaxf(xv.x * p0, 0.f);
  o.y = xv.y * ca + fmaxf(xv.y * p1, 0.f);
  o.z = xv.z * ca + fmaxf(xv.z * p2, 0.f);
  o.w = xv.w * ca + fmaxf(xv.w * p3, 0.f);
  *(float4*)(out + (size_t)gi * 4) = o;
}

// ---------------------------------------------------------------------------
extern "C" void kernel_launch(void* const* d_in, const int* in_sizes, int n_in,
                              void* d_out, int out_size, void* d_ws, size_t ws_size,
                              hipStream_t stream) {
  const float* x     = (const float*)d_in[0];
  const float* wdr   = (const float*)d_in[1];
  const float* bdr   = (const float*)d_in[2];
  const float* g1    = (const float*)d_in[3];
  const float* be1   = (const float*)d_in[4];
  const float* m1    = (const float*)d_in[5];
  const float* v1    = (const float*)d_in[6];
  const float* g2    = (const float*)d_in[7];
  const float* be2   = (const float*)d_in[8];
  const float* m2    = (const float*)d_in[9];
  const float* v2    = (const float*)d_in[10];
  const float* wrow  = (const float*)d_in[11];
  const float* brow  = (const float*)d_in[12];
  const float* wfc   = (const float*)d_in[13];
  const float* bfc   = (const float*)d_in[14];
  const float* wdrs  = (const float*)d_in[15];
  const float* bdrs  = (const float*)d_in[16];
  const float* g3    = (const float*)d_in[17];
  const float* be3   = (const float*)d_in[18];
  const float* m3    = (const float*)d_in[19];
  const float* v3    = (const float*)d_in[20];
  const float* g4    = (const float*)d_in[21];
  const float* be4   = (const float*)d_in[22];
  const float* m4    = (const float*)d_in[23];
  const float* v4    = (const float*)d_in[24];
  const float* wrows = (const float*)d_in[25];
  const float* brows = (const float*)d_in[26];
  const float* wfcs  = (const float*)d_in[27];
  const float* bfcs  = (const float*)d_in[28];

  // All large scratch lives in d_out (205 MB, fully overwritten by k_final
  // last). d_ws is used ONLY for catt+patt (72 KB), the tensors k_final
  // reads while overwriting d_out.
  char* ob = (char*)d_out;
  ushort* y_bf    = (ushort*)(ob + 0x0000000);  // 25.7 MB (consumed by k_gram)
  ushort* wdr_bf  = (ushort*)(ob + 0x2000000);  // 128 KB
  ushort* wdrs_bf = (ushort*)(ob + 0x2020000);  // 128 KB
  float*  sc1     = (float*) (ob + 0x2040000);  // 512 B
  float*  sh1     = (float*) (ob + 0x2040200);  // 512 B
  float*  wfcT    = (float*) (ob + 0x2050000);  // 1 MB
  float*  rp      = (float*) (ob + 0x2150000);  // 4 MB   [b][g][c]
  float*  G       = (float*) (ob + 0x2550000);  // 2 MB
  float*  S       = (float*) (ob + 0x2750000);  // 16 KB  (end 0x2754000 < 205MB)
  ushort* sfT     = (ushort*)(ob + 0x2760000);  // 512 KB [b][g][d]

  char* ws = (char*)d_ws;
  float* catt = (float*)(ws + 0x00000);         // 64 KB
  float* patt = (float*)(ws + 0x10000);         // 8 KB   (total ws use 72 KB)

  // zero atomic accumulators rp+G+S (contiguous 0x604000 B at 0x2150000)
  k_zero<<<1540, 256, 0, stream>>>((float4*)(ob + 0x2150000));

  k_prep<<<1024, 256, 0, stream>>>(wdr, wdrs, bdr, g1, be1, m1, v1, wfc,
                                   wdr_bf, wdrs_bf, sc1, sh1, wfcT);
  k_convy<<<dim3(25, 32), 256, 0, stream>>>(x, wdr_bf, sc1, sh1, y_bf, rp);
  k_gram<<<dim3(7, 32), 256, 0, stream>>>(y_bf, G, S);
  k_catt<<<32, 256, 0, stream>>>(G, S, g2, be2, m2, v2, wrow, brow, wfcT, bfc, catt);
  k_sconv<<<32, 256, 0, stream>>>(rp, wdrs_bf, bdrs, g3, be3, m3, v3, sfT);
  k_patt<<<32, 256, 0, stream>>>(sfT, g4, be4, m4, v4, wrows, brows, wfcs, bfcs, patt);
  k_final<<<50176, 256, 0, stream>>>(x, catt, patt, (float*)d_out);
}